// Round 9
// baseline (201.381 us; speedup 1.0000x reference)
//
#include <hip/hip_runtime.h>
#include <hip/hip_bf16.h>
#include <cstdint>
#include <cstddef>
#include <type_traits>

// B=4, S=2048, D=1024 causal attention head, fp32 in/out.
// R14: gemm128_core rebuilt as BK=32 / 4-deep double-sided pipeline.
// R13 counters: sc128 1588cyc/block-phase, MfmaUtil 14% — B(t+1) had only
// 1.5-phase cover; sc streams BOTH operands so B-misses stall every tile.
// New core: A and B both 4-buffered (64KB LDS, still 2 blocks/CU), stage(t+3)
// issued per phase, vmcnt(8)/4/0 ladder -> ~2.5-phase cover both sides.
// Used by sc and pv. qv256 / prep unchanged.

using bf16 = __hip_bfloat16;
typedef __attribute__((ext_vector_type(8))) short short8;   // 8 bf16 (A/B frag)
typedef __attribute__((ext_vector_type(4))) float f32x4;    // C/D frag

#define NB 4
#define SS 2048
#define DD 1024

// ---------------------------------------------------------------- async 16B global->LDS
__device__ __forceinline__ void async_lds16(const bf16* g, bf16* l) {
  __builtin_amdgcn_global_load_lds(
      (const __attribute__((address_space(1))) void*)g,
      (__attribute__((address_space(3))) void*)l,
      16, 0, 0);  // HW writes lane i's 16B to ldsbase + i*16
}

struct alignas(8) bf16x4s { bf16 a, b, c, d; };

// ---------------------------------------------------------------- fused prep
__global__ __launch_bounds__(256) void prep_kernel(const float* __restrict__ x,
                                                   bf16* __restrict__ xb,
                                                   const float* __restrict__ qk,
                                                   bf16* __restrict__ qkT,
                                                   const float* __restrict__ ov,
                                                   bf16* __restrict__ ovT,
                                                   float* __restrict__ l) {
  __shared__ bf16 tile[64][65];
  const int bx = blockIdx.x;
  if (bx < 8192) {
    int i = (bx * 256 + threadIdx.x) * 4;
    float4 v = *(const float4*)(x + i);
    bf16x4s o{__float2bfloat16(v.x), __float2bfloat16(v.y),
              __float2bfloat16(v.z), __float2bfloat16(v.w)};
    *(bf16x4s*)(xb + i) = o;
  } else if (bx < 8704) {
    const int idx = bx - 8192;
    const float* in = (idx & 256) ? ov : qk;
    bf16* out = (idx & 256) ? ovT : qkT;
    const int rem = idx & 255;
    const int tbx = (rem & 15) * 64;
    const int tby = (rem >> 4) * 64;
    const int tc = threadIdx.x & 63;
    const int tr = threadIdx.x >> 6;
#pragma unroll
    for (int r = tr; r < 64; r += 4)
      tile[tc][r] = __float2bfloat16(in[(size_t)(tby + r) * DD + tbx + tc]);
    __syncthreads();
#pragma unroll
    for (int r = tr; r < 64; r += 4)
      out[(size_t)(tbx + r) * DD + tby + tc] = tile[r][tc];
  } else {
    const int t = (bx - 8704) * 256 + threadIdx.x;
    f32x4 z = {0.f, 0.f, 0.f, 0.f};
    *(f32x4*)(l + t * 4) = z;
  }
}

// ================================================================ 256^2 phased core (R8/R10-validated)
// Used by qv only. EPI fixed = bf16 store.
__device__ __forceinline__ void gemm256_core(const bf16* __restrict__ Ab,
                                             const bf16* __restrict__ Bb,
                                             bf16* __restrict__ C,
                                             int N, int K, int m0, int n0, int nk,
                                             bf16* As, bf16* Bs) {
  const int lane = threadIdx.x & 63;
  const int wave = threadIdx.x >> 6;   // 0..7
  const int wr   = wave >> 2;          // 0..1 -> rows wr*128
  const int wc   = wave & 3;           // 0..3 -> cols wc*64
  const int quad = lane >> 4;
  const int r    = lane & 15;

  f32x4 acc[8][4];
#pragma unroll
  for (int i = 0; i < 8; ++i)
#pragma unroll
    for (int n = 0; n < 4; ++n) acc[i][n] = f32x4{0.f, 0.f, 0.f, 0.f};

  const int lrow = lane >> 3;
  const int lsw  = (lane & 7) ^ lrow;          // pre-swizzled source chunk
  const long long a_lane = (long long)(m0 + wave * 8 + lrow) * K + lsw * 8;
  const long long b_lane = (long long)(n0 + wave * 8 + lrow) * K + lsw * 8;

  auto stageA = [&](int kt, int rnd, int buf) {
    async_lds16(Ab + a_lane + (long long)(rnd * 64) * K + (long long)kt * 64,
                As + buf * 16384 + (rnd * 64 + wave * 8) * 64);
  };
  auto stageB = [&](int kt, int rnd, int buf) {
    async_lds16(Bb + b_lane + (long long)(rnd * 64) * K + (long long)kt * 64,
                Bs + buf * 16384 + (rnd * 64 + wave * 8) * 64);
  };

  stageA(0, 0, 0); stageA(0, 2, 0);
  stageB(0, 0, 0); stageB(0, 1, 0); stageB(0, 2, 0); stageB(0, 3, 0);
  stageA(0, 1, 0); stageA(0, 3, 0);
  asm volatile("s_waitcnt vmcnt(2)" ::: "memory");
  asm volatile("s_barrier" ::: "memory");

  const int ca0 = (quad ^ (r & 7)) * 8;        // kh=0 swizzled chunk offset
  const int ca1 = ((4 + quad) ^ (r & 7)) * 8;  // kh=1

  for (int kt = 0; kt < nk; ++kt) {
    const int buf = kt & 1, nxt = buf ^ 1;
    const bool hn = (kt + 1 < nk);
    const bf16* Abuf = As + buf * 16384 + (wr * 128) * 64;
    const bf16* Bbuf = Bs + buf * 16384 + (wc * 64) * 64;

    auto phase = [&](auto RHC, int ca, auto&& stg, int wmode) {
      constexpr int RH = decltype(RHC)::value;
      short8 af[4], bfr[4];
#pragma unroll
      for (int m = 0; m < 4; ++m)
        af[m] = *(const short8*)(Abuf + (RH * 64 + m * 16 + r) * 64 + ca);
#pragma unroll
      for (int n = 0; n < 4; ++n)
        bfr[n] = *(const short8*)(Bbuf + (n * 16 + r) * 64 + ca);
      stg();
      asm volatile("s_barrier" ::: "memory");
      asm volatile("s_waitcnt lgkmcnt(0)" ::: "memory");
      __builtin_amdgcn_sched_barrier(0);
      __builtin_amdgcn_s_setprio(1);
#pragma unroll
      for (int m = 0; m < 4; ++m)
#pragma unroll
        for (int n = 0; n < 4; ++n)
          acc[RH * 4 + m][n] = __builtin_amdgcn_mfma_f32_16x16x32_bf16(
              af[m], bfr[n], acc[RH * 4 + m][n], 0, 0, 0);
      __builtin_amdgcn_s_setprio(0);
      if (wmode == 1) {
        if (hn) asm volatile("s_waitcnt vmcnt(2)" ::: "memory");
        else    asm volatile("s_waitcnt vmcnt(0)" ::: "memory");
      } else if (wmode == 2) {
        if (hn) asm volatile("s_waitcnt vmcnt(2)" ::: "memory");
      }
      asm volatile("s_barrier" ::: "memory");
    };

    phase(std::integral_constant<int, 0>{}, ca0,
          [&] { if (hn) { stageA(kt + 1, 0, nxt); stageA(kt + 1, 2, nxt); } }, 1);
    phase(std::integral_constant<int, 1>{}, ca0,
          [&] { if (hn) { stageB(kt + 1, 0, nxt); stageB(kt + 1, 1, nxt); } }, 0);
    phase(std::integral_constant<int, 0>{}, ca1,
          [&] { if (hn) { stageB(kt + 1, 2, nxt); stageB(kt + 1, 3, nxt); } }, 0);
    phase(std::integral_constant<int, 1>{}, ca1,
          [&] { if (hn) { stageA(kt + 1, 1, nxt); stageA(kt + 1, 3, nxt); } }, 2);
  }

  // epilogue: C/D layout col = lane&15, row = quad*4 + reg (verified m89/m91)
#pragma unroll
  for (int i = 0; i < 8; ++i) {
    const int row0 = m0 + wr * 128 + i * 16 + quad * 4;
#pragma unroll
    for (int n = 0; n < 4; ++n) {
      const int col = n0 + wc * 64 + n * 16 + r;
#pragma unroll
      for (int q = 0; q < 4; ++q)
        C[(long long)(row0 + q) * N + col] = __float2bfloat16(acc[i][n][q]);
    }
  }
}

// ================================================================ 128^2 BK=32 4-deep core
// 128x128 tile, BK=32, 4 waves (2Mx2N), acc[4][4] per wave (64x64 out).
// One phase per K-tile: 8 ds_read_b128 + 16 MFMA per wave, stage(t+3) issued
// mid-phase. A and B BOTH 4-buffered (buf = t&3): tile t+1's loads are waited
// at end of phase t (vmcnt(8): retires oldest 4 = t+1) — issued at phase t-2,
// ~2.5-phase cover for BOTH streaming operands. 64KB LDS -> 2 blocks/CU.
// Swizzle (T2, both-sides): read chunk = quad^(r&3); staging source
// pre-swizzled with (lane&3)^(lrow&3), linear gload_lds dest.
// EPI: 2 = exp(acc/32) causal -> bf16 + rowsum atomics; 3 = acc/l[row] f32.
template <int EPI>
__device__ __forceinline__ void gemm128_core(const bf16* __restrict__ Ab,
                                             const bf16* __restrict__ Bb,
                                             void* __restrict__ C,
                                             float* __restrict__ l,
                                             int N, int K, int m0, int n0, int nk,
                                             bf16* As, bf16* Bs) {
  const int lane = threadIdx.x & 63;
  const int wave = threadIdx.x >> 6;   // 0..3
  const int wr   = wave >> 1;          // 0..1 -> rows wr*64
  const int wc   = wave & 1;           // 0..1 -> cols wc*64
  const int quad = lane >> 4;
  const int r    = lane & 15;

  f32x4 acc[4][4];
#pragma unroll
  for (int m = 0; m < 4; ++m)
#pragma unroll
    for (int n = 0; n < 4; ++n) acc[m][n] = f32x4{0.f, 0.f, 0.f, 0.f};

  // staging: per wave-call 64 lanes x 16B = 1KB = 16 rows of [*][32] (64B rows).
  // lane l -> row l>>2, phys chunk l&3; logical chunk = (l&3)^(lrow&3).
  const int lrow = lane >> 2;                  // 0..15
  const int lsw  = (lane & 3) ^ (lrow & 3);    // pre-swizzled source chunk (T2)
  const long long a_base = (long long)(m0 + wave * 32 + lrow) * K + lsw * 8;
  const long long b_base = (long long)(n0 + wave * 32 + lrow) * K + lsw * 8;

  auto stageA = [&](int kt, int buf) {
#pragma unroll
    for (int i = 0; i < 2; ++i)
      async_lds16(Ab + a_base + (long long)(i * 16) * K + (long long)kt * 32,
                  As + buf * 4096 + (wave * 32 + i * 16) * 32);
  };
  auto stageB = [&](int kt, int buf) {
#pragma unroll
    for (int i = 0; i < 2; ++i)
      async_lds16(Bb + b_base + (long long)(i * 16) * K + (long long)kt * 32,
                  Bs + buf * 4096 + (wave * 32 + i * 16) * 32);
  };

  // prologue: tiles 0,1,2 into bufs 0,1,2 (4 loads each).
  stageB(0, 0); stageA(0, 0);
  if (nk > 1) { stageB(1, 1); stageA(1, 1); }
  if (nk > 2) { stageB(2, 2); stageA(2, 2); }
  if (nk > 2)      asm volatile("s_waitcnt vmcnt(8)" ::: "memory");
  else if (nk > 1) asm volatile("s_waitcnt vmcnt(4)" ::: "memory");
  else             asm volatile("s_waitcnt vmcnt(0)" ::: "memory");
  asm volatile("s_barrier" ::: "memory");

  const int ca = (quad ^ (r & 3)) * 8;         // swizzled chunk offset (elems)

  for (int t = 0; t < nk; ++t) {
    const int bt = t & 3, b3 = (t + 3) & 3;
    const bf16* Abuf = As + bt * 4096;
    const bf16* Bbuf = Bs + bt * 4096;

    short8 af[4], bfr[4];
#pragma unroll
    for (int m = 0; m < 4; ++m)
      af[m] = *(const short8*)(Abuf + (wr * 64 + m * 16 + r) * 32 + ca);
#pragma unroll
    for (int n = 0; n < 4; ++n)
      bfr[n] = *(const short8*)(Bbuf + (wc * 64 + n * 16 + r) * 32 + ca);

    if (t + 3 < nk) { stageB(t + 3, b3); stageA(t + 3, b3); }

    asm volatile("s_barrier" ::: "memory");
    asm volatile("s_waitcnt lgkmcnt(0)" ::: "memory");
    __builtin_amdgcn_sched_barrier(0);
    __builtin_amdgcn_s_setprio(1);
#pragma unroll
    for (int m = 0; m < 4; ++m)
#pragma unroll
      for (int n = 0; n < 4; ++n)
        acc[m][n] = __builtin_amdgcn_mfma_f32_16x16x32_bf16(
            af[m], bfr[n], acc[m][n], 0, 0, 0);
    __builtin_amdgcn_s_setprio(0);

    if (t + 3 < nk)      asm volatile("s_waitcnt vmcnt(8)" ::: "memory");
    else if (t + 2 < nk) asm volatile("s_waitcnt vmcnt(4)" ::: "memory");
    else if (t + 1 < nk) asm volatile("s_waitcnt vmcnt(0)" ::: "memory");
    asm volatile("s_barrier" ::: "memory");
  }

  // epilogue: C/D layout col = lane&15, row = quad*4 + reg (verified m89/m91)
#pragma unroll
  for (int m = 0; m < 4; ++m) {
    const int row0 = m0 + wr * 64 + m * 16 + quad * 4;
    if (EPI == 2) {
      float qs[4] = {0.f, 0.f, 0.f, 0.f};
#pragma unroll
      for (int n = 0; n < 4; ++n) {
        const int col = n0 + wc * 64 + n * 16 + r;
#pragma unroll
        for (int q = 0; q < 4; ++q) {
          const int row = row0 + q;
          float v = (col <= row) ? __expf(acc[m][n][q] * 0.03125f) : 0.0f;
          ((bf16*)C)[(long long)row * N + col] = __float2bfloat16(v);
          qs[q] += v;
        }
      }
#pragma unroll
      for (int q = 0; q < 4; ++q) {
#pragma unroll
        for (int off = 1; off < 16; off <<= 1) qs[q] += __shfl_xor(qs[q], off, 64);
        if (r == 0) atomicAdd(&l[row0 + q], qs[q]);
      }
    } else {  // EPI == 3
      float rs[4];
#pragma unroll
      for (int q = 0; q < 4; ++q) rs[q] = 1.0f / l[row0 + q];
#pragma unroll
      for (int n = 0; n < 4; ++n) {
        const int col = n0 + wc * 64 + n * 16 + r;
#pragma unroll
        for (int q = 0; q < 4; ++q)
          ((float*)C)[(long long)(row0 + q) * N + col] = acc[m][n][q] * rs[q];
      }
    }
  }
}

// ---------------------------------------------------------------- merged Q + V GEMM (256^2)
__global__ __launch_bounds__(512, 2) void gemm_qv256(const bf16* __restrict__ xb,
                                                     const bf16* __restrict__ qkT,
                                                     const bf16* __restrict__ ovT,
                                                     bf16* __restrict__ Qb,
                                                     bf16* __restrict__ Vt) {
  extern __shared__ bf16 lds[];
  bf16* As = lds;            // [2][256][64]
  bf16* Bs = lds + 32768;    // [2][256][64]
  const long long SD = (long long)SS * DD;
  const int z = blockIdx.z;
  if (z < 4) {
    const int bn = blockIdx.x & 3, bm = blockIdx.x >> 2;
    gemm256_core(xb + z * SD, qkT, Qb + z * SD, DD, DD, bm * 256, bn * 256, 16, As, Bs);
  } else {
    const int bm = blockIdx.x & 3, bn = blockIdx.x >> 2;
    gemm256_core(ovT, xb + (z - 4) * SD, Vt + (z - 4) * SD, SS, DD, bm * 256, bn * 256, 16, As, Bs);
  }
}

// ---------------------------------------------------------------- scores GEMM (128^2) + exp/mask/rowsum
// 136 causal tiles x 4 batches = 544 uniform jobs (nk=32 at BK=32), 2/CU.
__global__ __launch_bounds__(256, 2) void gemm_sc128(const bf16* __restrict__ Qb,
                                                     const bf16* __restrict__ xb,
                                                     bf16* __restrict__ P,
                                                     float* __restrict__ l) {
  extern __shared__ bf16 lds[];
  bf16* As = lds;            // [4][128][32] = 32KB
  bf16* Bs = lds + 16384;    // [4][128][32] = 32KB
  const long long SD = (long long)SS * DD;
  const long long SSQ = (long long)SS * SS;
  const int t = blockIdx.x;
  int bm = (int)((sqrtf(8.0f * (float)t + 1.0f) - 1.0f) * 0.5f);
  while ((bm + 1) * (bm + 2) / 2 <= t) ++bm;
  while (bm * (bm + 1) / 2 > t) --bm;
  const int bn = t - bm * (bm + 1) / 2;
  const int b = blockIdx.z;
  gemm128_core<2>(Qb + b * SD, xb + b * SD, P + b * SSQ, l + b * SS,
                  SS, DD, bm * 128, bn * 128, 32, As, Bs);
}

// ---------------------------------------------------------------- PV GEMM (128^2, balanced pairs)
// Grid (64,1,4): c = x&7 (128-wide D col-tile), pr = x>>3 (strip pair).
// Block does strip 15-pr (nk=4(16-pr)) then strip pr (nk=4(pr+1)):
// exactly 68 BK32-tiles per block, 256 blocks, 2 blocks/CU.
__global__ __launch_bounds__(256, 2) void gemm_pv128(const bf16* __restrict__ P,
                                                     const bf16* __restrict__ Vt,
                                                     float* __restrict__ l,
                                                     float* __restrict__ out) {
  extern __shared__ bf16 lds[];
  bf16* As = lds;            // [4][128][32] = 32KB
  bf16* Bs = lds + 16384;    // [4][128][32] = 32KB
  const long long SD = (long long)SS * DD;
  const long long SSQ = (long long)SS * SS;
  const int c  = blockIdx.x & 7;
  const int pr = blockIdx.x >> 3;
  const int b  = blockIdx.z;
  const int n0 = c * 128;
  const int rL = 15 - pr;
  gemm128_core<3>(P + b * SSQ, Vt + b * SD, out + b * SD, l + b * SS,
                  DD, SS, rL * 128, n0, 4 * (rL + 1), As, Bs);
  __syncthreads();
  gemm128_core<3>(P + b * SSQ, Vt + b * SD, out + b * SD, l + b * SS,
                  DD, SS, pr * 128, n0, 4 * (pr + 1), As, Bs);
}

// ---------------------------------------------------------------- launch
extern "C" void kernel_launch(void* const* d_in, const int* in_sizes, int n_in,
                              void* d_out, int out_size, void* d_ws, size_t ws_size,
                              hipStream_t stream) {
  const float* x  = (const float*)d_in[0];  // [4,2048,1024]
  const float* qk = (const float*)d_in[1];  // [1024,1024]
  const float* ov = (const float*)d_in[2];  // [1024,1024]
  float* out = (float*)d_out;               // [4,2048,1024] fp32

  char* ws = (char*)d_ws;
  const size_t MB = 1ull << 20;
  bf16*  xb  = (bf16*)(ws + 0);          // 16 MB
  bf16*  qkT = (bf16*)(ws + 16 * MB);    //  2 MB
  bf16*  ovT = (bf16*)(ws + 18 * MB);    //  2 MB
  bf16*  Qb  = (bf16*)(ws + 20 * MB);    // 16 MB
  bf16*  Vt  = (bf16*)(ws + 36 * MB);    // 16 MB  V^T per batch [D, S]
  bf16*  P   = (bf16*)(ws + 52 * MB);    // 32 MB  P' = exp(s/32) bf16
  float* l   = (float*)(ws + 84 * MB);   // 32 KB  row sums [B][S]

  static bool lds_opt_in = false;
  if (!lds_opt_in) {
    hipFuncSetAttribute((const void*)gemm_qv256,
                        hipFuncAttributeMaxDynamicSharedMemorySize, 131072);
    hipFuncSetAttribute((const void*)gemm_sc128,
                        hipFuncAttributeMaxDynamicSharedMemorySize, 65536);
    hipFuncSetAttribute((const void*)gemm_pv128,
                        hipFuncAttributeMaxDynamicSharedMemorySize, 65536);
    lds_opt_in = true;
  }

  prep_kernel<<<dim3(8712), 256, 0, stream>>>(x, xb, qk, qkT, ov, ovT, l);
  gemm_qv256<<<dim3(32, 1, 8), 512, 131072, stream>>>(xb, qkT, ovT, Qb, Vt);
  gemm_sc128<<<dim3(136, 1, 4), 256, 65536, stream>>>(Qb, xb, P, l);
  gemm_pv128<<<dim3(64, 1, 4), 256, 65536, stream>>>(P, Vt, l, out);
}

// Round 10
// 190.924 us; speedup vs baseline: 1.0548x; 1.0548x over previous
//
#include <hip/hip_runtime.h>
#include <hip/hip_bf16.h>
#include <cstdint>
#include <cstddef>
#include <type_traits>

// B=4, S=2048, D=1024 causal attention head, fp32 in/out.
// R15: sc rebuilt as 64x128 jobs (1088 blocks, 48KB LDS -> 3 blocks/CU,
// 12 waves/CU). R14 evidence: BK=32 swizzle caused 4-way conflicts (2.23M);
// reverted. R12/R13 paradox explained by grid-tail: 544 = 2x256+32 leaves a
// ~20us 32-block tail; finer jobs cut ceil-overage 1.41x -> 1.18x and triple
// block residency. pv restored to R13-exact (best measured). qv/prep kept.

using bf16 = __hip_bfloat16;
typedef __attribute__((ext_vector_type(8))) short short8;   // 8 bf16 (A/B frag)
typedef __attribute__((ext_vector_type(4))) float f32x4;    // C/D frag

#define NB 4
#define SS 2048
#define DD 1024

// ---------------------------------------------------------------- async 16B global->LDS
__device__ __forceinline__ void async_lds16(const bf16* g, bf16* l) {
  __builtin_amdgcn_global_load_lds(
      (const __attribute__((address_space(1))) void*)g,
      (__attribute__((address_space(3))) void*)l,
      16, 0, 0);  // HW writes lane i's 16B to ldsbase + i*16
}

struct alignas(8) bf16x4s { bf16 a, b, c, d; };

// ---------------------------------------------------------------- fused prep
__global__ __launch_bounds__(256) void prep_kernel(const float* __restrict__ x,
                                                   bf16* __restrict__ xb,
                                                   const float* __restrict__ qk,
                                                   bf16* __restrict__ qkT,
                                                   const float* __restrict__ ov,
                                                   bf16* __restrict__ ovT,
                                                   float* __restrict__ l) {
  __shared__ bf16 tile[64][65];
  const int bx = blockIdx.x;
  if (bx < 8192) {
    int i = (bx * 256 + threadIdx.x) * 4;
    float4 v = *(const float4*)(x + i);
    bf16x4s o{__float2bfloat16(v.x), __float2bfloat16(v.y),
              __float2bfloat16(v.z), __float2bfloat16(v.w)};
    *(bf16x4s*)(xb + i) = o;
  } else if (bx < 8704) {
    const int idx = bx - 8192;
    const float* in = (idx & 256) ? ov : qk;
    bf16* out = (idx & 256) ? ovT : qkT;
    const int rem = idx & 255;
    const int tbx = (rem & 15) * 64;
    const int tby = (rem >> 4) * 64;
    const int tc = threadIdx.x & 63;
    const int tr = threadIdx.x >> 6;
#pragma unroll
    for (int r = tr; r < 64; r += 4)
      tile[tc][r] = __float2bfloat16(in[(size_t)(tby + r) * DD + tbx + tc]);
    __syncthreads();
#pragma unroll
    for (int r = tr; r < 64; r += 4)
      out[(size_t)(tbx + r) * DD + tby + tc] = tile[r][tc];
  } else {
    const int t = (bx - 8704) * 256 + threadIdx.x;
    f32x4 z = {0.f, 0.f, 0.f, 0.f};
    *(f32x4*)(l + t * 4) = z;
  }
}

// ================================================================ 256^2 phased core (R8/R10-validated)
// Used by qv only. EPI fixed = bf16 store.
__device__ __forceinline__ void gemm256_core(const bf16* __restrict__ Ab,
                                             const bf16* __restrict__ Bb,
                                             bf16* __restrict__ C,
                                             int N, int K, int m0, int n0, int nk,
                                             bf16* As, bf16* Bs) {
  const int lane = threadIdx.x & 63;
  const int wave = threadIdx.x >> 6;   // 0..7
  const int wr   = wave >> 2;          // 0..1 -> rows wr*128
  const int wc   = wave & 3;           // 0..3 -> cols wc*64
  const int quad = lane >> 4;
  const int r    = lane & 15;

  f32x4 acc[8][4];
#pragma unroll
  for (int i = 0; i < 8; ++i)
#pragma unroll
    for (int n = 0; n < 4; ++n) acc[i][n] = f32x4{0.f, 0.f, 0.f, 0.f};

  const int lrow = lane >> 3;
  const int lsw  = (lane & 7) ^ lrow;          // pre-swizzled source chunk
  const long long a_lane = (long long)(m0 + wave * 8 + lrow) * K + lsw * 8;
  const long long b_lane = (long long)(n0 + wave * 8 + lrow) * K + lsw * 8;

  auto stageA = [&](int kt, int rnd, int buf) {
    async_lds16(Ab + a_lane + (long long)(rnd * 64) * K + (long long)kt * 64,
                As + buf * 16384 + (rnd * 64 + wave * 8) * 64);
  };
  auto stageB = [&](int kt, int rnd, int buf) {
    async_lds16(Bb + b_lane + (long long)(rnd * 64) * K + (long long)kt * 64,
                Bs + buf * 16384 + (rnd * 64 + wave * 8) * 64);
  };

  stageA(0, 0, 0); stageA(0, 2, 0);
  stageB(0, 0, 0); stageB(0, 1, 0); stageB(0, 2, 0); stageB(0, 3, 0);
  stageA(0, 1, 0); stageA(0, 3, 0);
  asm volatile("s_waitcnt vmcnt(2)" ::: "memory");
  asm volatile("s_barrier" ::: "memory");

  const int ca0 = (quad ^ (r & 7)) * 8;        // kh=0 swizzled chunk offset
  const int ca1 = ((4 + quad) ^ (r & 7)) * 8;  // kh=1

  for (int kt = 0; kt < nk; ++kt) {
    const int buf = kt & 1, nxt = buf ^ 1;
    const bool hn = (kt + 1 < nk);
    const bf16* Abuf = As + buf * 16384 + (wr * 128) * 64;
    const bf16* Bbuf = Bs + buf * 16384 + (wc * 64) * 64;

    auto phase = [&](auto RHC, int ca, auto&& stg, int wmode) {
      constexpr int RH = decltype(RHC)::value;
      short8 af[4], bfr[4];
#pragma unroll
      for (int m = 0; m < 4; ++m)
        af[m] = *(const short8*)(Abuf + (RH * 64 + m * 16 + r) * 64 + ca);
#pragma unroll
      for (int n = 0; n < 4; ++n)
        bfr[n] = *(const short8*)(Bbuf + (n * 16 + r) * 64 + ca);
      stg();
      asm volatile("s_barrier" ::: "memory");
      asm volatile("s_waitcnt lgkmcnt(0)" ::: "memory");
      __builtin_amdgcn_sched_barrier(0);
      __builtin_amdgcn_s_setprio(1);
#pragma unroll
      for (int m = 0; m < 4; ++m)
#pragma unroll
        for (int n = 0; n < 4; ++n)
          acc[RH * 4 + m][n] = __builtin_amdgcn_mfma_f32_16x16x32_bf16(
              af[m], bfr[n], acc[RH * 4 + m][n], 0, 0, 0);
      __builtin_amdgcn_s_setprio(0);
      if (wmode == 1) {
        if (hn) asm volatile("s_waitcnt vmcnt(2)" ::: "memory");
        else    asm volatile("s_waitcnt vmcnt(0)" ::: "memory");
      } else if (wmode == 2) {
        if (hn) asm volatile("s_waitcnt vmcnt(2)" ::: "memory");
      }
      asm volatile("s_barrier" ::: "memory");
    };

    phase(std::integral_constant<int, 0>{}, ca0,
          [&] { if (hn) { stageA(kt + 1, 0, nxt); stageA(kt + 1, 2, nxt); } }, 1);
    phase(std::integral_constant<int, 1>{}, ca0,
          [&] { if (hn) { stageB(kt + 1, 0, nxt); stageB(kt + 1, 1, nxt); } }, 0);
    phase(std::integral_constant<int, 0>{}, ca1,
          [&] { if (hn) { stageB(kt + 1, 2, nxt); stageB(kt + 1, 3, nxt); } }, 0);
    phase(std::integral_constant<int, 1>{}, ca1,
          [&] { if (hn) { stageA(kt + 1, 1, nxt); stageA(kt + 1, 3, nxt); } }, 2);
  }

  // epilogue: C/D layout col = lane&15, row = quad*4 + reg (verified m89/m91)
#pragma unroll
  for (int i = 0; i < 8; ++i) {
    const int row0 = m0 + wr * 128 + i * 16 + quad * 4;
#pragma unroll
    for (int n = 0; n < 4; ++n) {
      const int col = n0 + wc * 64 + n * 16 + r;
#pragma unroll
      for (int q = 0; q < 4; ++q)
        C[(long long)(row0 + q) * N + col] = __float2bfloat16(acc[i][n][q]);
    }
  }
}

// ================================================================ 64x128 4-wave 2-phase core (sc)
// M=64, N=128, BK=64. Waves 2Mx2N: wave = 32x64, acc[2][4]. Per phase:
// 6 ds_read_b128 + 8 MFMA + 3 stage calls. LDS 48KB (A[2][64][64] 16KB +
// B[2][128][64] 32KB) -> 3 blocks/CU = 12 waves/CU. Proven 128B-row swizzle
// (chunk XOR r&7, zero conflicts R10-R13). End-of-tile vmcnt(0) drain is
// covered by the 3 independent co-resident blocks (R12 mechanism).
// EPI=2: exp(acc/32) causal -> bf16 P + rowsum atomics.
__device__ __forceinline__ void gemm64_sc(const bf16* __restrict__ Ab,
                                          const bf16* __restrict__ Bb,
                                          bf16* __restrict__ P,
                                          float* __restrict__ l,
                                          int N, int K, int m0, int n0, int nk,
                                          bf16* As, bf16* Bs) {
  const int lane = threadIdx.x & 63;
  const int wave = threadIdx.x >> 6;   // 0..3
  const int wm   = (wave >> 1) * 32;   // rows wm..wm+31
  const int wn   = (wave & 1) * 64;    // cols wn..wn+63
  const int quad = lane >> 4;
  const int r    = lane & 15;

  f32x4 acc[2][4];
#pragma unroll
  for (int m = 0; m < 2; ++m)
#pragma unroll
    for (int n = 0; n < 4; ++n) acc[m][n] = f32x4{0.f, 0.f, 0.f, 0.f};

  const int lrow = lane >> 3;                  // 8 rows per wave-call (128B rows)
  const int lsw  = (lane & 7) ^ lrow;          // pre-swizzled source chunk (T2)
  const long long a_lane = (long long)(m0 + lrow) * K + lsw * 8;
  const long long b_lane = (long long)(n0 + lrow) * K + lsw * 8;

  // A: 64 rows = 2 rounds of 32 (4 waves x 8 rows); B: 128 rows = 4 rounds.
  auto stageA = [&](int kt, int rnd, int buf) {
    async_lds16(Ab + a_lane + (long long)(rnd * 32 + wave * 8) * K + (long long)kt * 64,
                As + buf * 4096 + (rnd * 32 + wave * 8) * 64);
  };
  auto stageB = [&](int kt, int rnd, int buf) {
    async_lds16(Bb + b_lane + (long long)(rnd * 32 + wave * 8) * K + (long long)kt * 64,
                Bs + buf * 8192 + (rnd * 32 + wave * 8) * 64);
  };

  // prologue: tile 0 -> buf 0 (6 calls), drain, barrier.
  stageA(0, 0, 0); stageA(0, 1, 0);
  stageB(0, 0, 0); stageB(0, 1, 0); stageB(0, 2, 0); stageB(0, 3, 0);
  asm volatile("s_waitcnt vmcnt(0)" ::: "memory");
  asm volatile("s_barrier" ::: "memory");

  const int ca0 = (quad ^ (r & 7)) * 8;        // kh=0 swizzled chunk (elems)
  const int ca1 = ((4 + quad) ^ (r & 7)) * 8;  // kh=1

  for (int kt = 0; kt < nk; ++kt) {
    const int buf = kt & 1, nxt = buf ^ 1;
    const bool hn = (kt + 1 < nk);
    const bf16* Abuf = As + buf * 4096;
    const bf16* Bbuf = Bs + buf * 8192;

    auto phase = [&](int ca, auto&& stg, bool tail) {
      short8 af[2], bfr[4];
#pragma unroll
      for (int m = 0; m < 2; ++m)
        af[m] = *(const short8*)(Abuf + (wm + m * 16 + r) * 64 + ca);
#pragma unroll
      for (int n = 0; n < 4; ++n)
        bfr[n] = *(const short8*)(Bbuf + (wn + n * 16 + r) * 64 + ca);
      stg();
      asm volatile("s_barrier" ::: "memory");
      asm volatile("s_waitcnt lgkmcnt(0)" ::: "memory");
      __builtin_amdgcn_sched_barrier(0);
      __builtin_amdgcn_s_setprio(1);
#pragma unroll
      for (int m = 0; m < 2; ++m)
#pragma unroll
        for (int n = 0; n < 4; ++n)
          acc[m][n] = __builtin_amdgcn_mfma_f32_16x16x32_bf16(
              af[m], bfr[n], acc[m][n], 0, 0, 0);
      __builtin_amdgcn_s_setprio(0);
      if (tail && hn) asm volatile("s_waitcnt vmcnt(0)" ::: "memory");
      asm volatile("s_barrier" ::: "memory");
    };

    phase(ca0, [&] { if (hn) { stageA(kt + 1, 0, nxt); stageA(kt + 1, 1, nxt);
                               stageB(kt + 1, 0, nxt); } }, false);
    phase(ca1, [&] { if (hn) { stageB(kt + 1, 1, nxt); stageB(kt + 1, 2, nxt);
                               stageB(kt + 1, 3, nxt); } }, true);
  }

  // epilogue: exp/mask/store + rowsum atomics (C/D layout verified m89/m91)
#pragma unroll
  for (int m = 0; m < 2; ++m) {
    const int row0 = m0 + wm + m * 16 + quad * 4;
    float qs[4] = {0.f, 0.f, 0.f, 0.f};
#pragma unroll
    for (int n = 0; n < 4; ++n) {
      const int col = n0 + wn + n * 16 + r;
#pragma unroll
      for (int q = 0; q < 4; ++q) {
        const int row = row0 + q;
        float v = (col <= row) ? __expf(acc[m][n][q] * 0.03125f) : 0.0f;
        P[(long long)row * N + col] = __float2bfloat16(v);
        qs[q] += v;
      }
    }
#pragma unroll
    for (int q = 0; q < 4; ++q) {
#pragma unroll
      for (int off = 1; off < 16; off <<= 1) qs[q] += __shfl_xor(qs[q], off, 64);
      if (r == 0) atomicAdd(&l[row0 + q], qs[q]);
    }
  }
}

// ================================================================ 128^2 4-wave 2-phase core (pv, R13-exact)
// LDS 80KB: A 3-buf (streaming P), B 2-buf (L2-warm Vt). Ph0 issues
// B(t+1)+A(t+2); end-of-tile vmcnt(4) retires {A(t+1),B(t),B(t+1)},
// keeps A(t+2). EPI=3: acc * (1/l[row]) -> f32.
__device__ __forceinline__ void gemm128_pv(const bf16* __restrict__ Ab,
                                           const bf16* __restrict__ Bb,
                                           float* __restrict__ C,
                                           const float* __restrict__ l,
                                           int N, int K, int m0, int n0, int nk,
                                           bf16* As, bf16* Bs) {
  const int lane = threadIdx.x & 63;
  const int wave = threadIdx.x >> 6;   // 0..3
  const int wr   = wave >> 1;          // 0..1 -> rows wr*64
  const int wc   = wave & 1;           // 0..1 -> cols wc*64
  const int quad = lane >> 4;
  const int r    = lane & 15;

  f32x4 acc[4][4];
#pragma unroll
  for (int m = 0; m < 4; ++m)
#pragma unroll
    for (int n = 0; n < 4; ++n) acc[m][n] = f32x4{0.f, 0.f, 0.f, 0.f};

  const int lrow = lane >> 3;
  const int lsw  = (lane & 7) ^ lrow;  // pre-swizzled source chunk (T2)
  const long long a_base = (long long)(m0 + wave * 32 + lrow) * K + lsw * 8;
  const long long b_base = (long long)(n0 + wave * 32 + lrow) * K + lsw * 8;

  auto stageA = [&](int kt, int buf) {
#pragma unroll
    for (int i = 0; i < 4; ++i)
      async_lds16(Ab + a_base + (long long)(i * 8) * K + (long long)kt * 64,
                  As + buf * 8192 + (wave * 32 + i * 8) * 64);
  };
  auto stageB = [&](int kt, int buf) {
#pragma unroll
    for (int i = 0; i < 4; ++i)
      async_lds16(Bb + b_base + (long long)(i * 8) * K + (long long)kt * 64,
                  Bs + buf * 8192 + (wave * 32 + i * 8) * 64);
  };

  // prologue: B(0),A(0)->buf0; A(1)->bufA1. vmcnt(4) keeps A(1) in flight.
  stageB(0, 0); stageA(0, 0); stageA(1, 1);
  asm volatile("s_waitcnt vmcnt(4)" ::: "memory");
  asm volatile("s_barrier" ::: "memory");

  const int ca0 = (quad ^ (r & 7)) * 8;
  const int ca1 = ((4 + quad) ^ (r & 7)) * 8;

  int ba = 0;                           // A buffer = kt % 3
  for (int kt = 0; kt < nk; ++kt) {
    const int bb = kt & 1;
    int ba2 = ba + 2; if (ba2 >= 3) ba2 -= 3;
    const bool hA = (kt + 2 < nk), hB = (kt + 1 < nk);
    const bf16* Abuf = As + ba * 8192;
    const bf16* Bbuf = Bs + bb * 8192;

    auto phase = [&](int ca, auto&& stg, bool tail) {
      short8 af[4], bfr[4];
#pragma unroll
      for (int m = 0; m < 4; ++m)
        af[m] = *(const short8*)(Abuf + (wr * 64 + m * 16 + r) * 64 + ca);
#pragma unroll
      for (int n = 0; n < 4; ++n)
        bfr[n] = *(const short8*)(Bbuf + (wc * 64 + n * 16 + r) * 64 + ca);
      stg();
      asm volatile("s_barrier" ::: "memory");
      asm volatile("s_waitcnt lgkmcnt(0)" ::: "memory");
      __builtin_amdgcn_sched_barrier(0);
      __builtin_amdgcn_s_setprio(1);
#pragma unroll
      for (int m = 0; m < 4; ++m)
#pragma unroll
        for (int n = 0; n < 4; ++n)
          acc[m][n] = __builtin_amdgcn_mfma_f32_16x16x32_bf16(
              af[m], bfr[n], acc[m][n], 0, 0, 0);
      __builtin_amdgcn_s_setprio(0);
      if (tail) {
        if (hA)      asm volatile("s_waitcnt vmcnt(4)" ::: "memory");
        else if (hB) asm volatile("s_waitcnt vmcnt(0)" ::: "memory");
      }
      asm volatile("s_barrier" ::: "memory");
    };

    phase(ca0, [&] { if (hB) stageB(kt + 1, bb ^ 1);
                     if (hA) stageA(kt + 2, ba2); }, false);
    phase(ca1, [&] {}, true);

    if (++ba == 3) ba = 0;
  }

  // epilogue: acc * (1/l[row]) -> f32
#pragma unroll
  for (int m = 0; m < 4; ++m) {
    const int row0 = m0 + wr * 64 + m * 16 + quad * 4;
    float rs[4];
#pragma unroll
    for (int q = 0; q < 4; ++q) rs[q] = 1.0f / l[row0 + q];
#pragma unroll
    for (int n = 0; n < 4; ++n) {
      const int col = n0 + wc * 64 + n * 16 + r;
#pragma unroll
      for (int q = 0; q < 4; ++q)
        C[(long long)(row0 + q) * N + col] = acc[m][n][q] * rs[q];
    }
  }
}

// ---------------------------------------------------------------- merged Q + V GEMM (256^2)
__global__ __launch_bounds__(512, 2) void gemm_qv256(const bf16* __restrict__ xb,
                                                     const bf16* __restrict__ qkT,
                                                     const bf16* __restrict__ ovT,
                                                     bf16* __restrict__ Qb,
                                                     bf16* __restrict__ Vt) {
  extern __shared__ bf16 lds[];
  bf16* As = lds;            // [2][256][64]
  bf16* Bs = lds + 32768;    // [2][256][64]
  const long long SD = (long long)SS * DD;
  const int z = blockIdx.z;
  if (z < 4) {
    const int bn = blockIdx.x & 3, bm = blockIdx.x >> 2;
    gemm256_core(xb + z * SD, qkT, Qb + z * SD, DD, DD, bm * 256, bn * 256, 16, As, Bs);
  } else {
    const int bm = blockIdx.x & 3, bn = blockIdx.x >> 2;
    gemm256_core(ovT, xb + (z - 4) * SD, Vt + (z - 4) * SD, SS, DD, bm * 256, bn * 256, 16, As, Bs);
  }
}

// ---------------------------------------------------------------- scores GEMM (64x128) + exp/mask/rowsum
// 272 causal 64x128 tiles per batch x 4 = 1088 uniform jobs (nk=16), 3/CU.
// Strip s (64 rows), col-tile c (128 cols): count(s) = s/2+1.
// cum: s=2k -> k(k+1); s=2k+1 -> (k+1)^2.
__global__ __launch_bounds__(256, 3) void gemm_sc64(const bf16* __restrict__ Qb,
                                                    const bf16* __restrict__ xb,
                                                    bf16* __restrict__ P,
                                                    float* __restrict__ l) {
  extern __shared__ bf16 lds[];
  bf16* As = lds;            // [2][64][64]  = 16KB
  bf16* Bs = lds + 8192;     // [2][128][64] = 32KB
  const long long SD = (long long)SS * DD;
  const long long SSQ = (long long)SS * SS;
  const int t = blockIdx.x;            // 0..271
  int k = (int)((sqrtf(4.0f * (float)t + 1.0f) - 1.0f) * 0.5f);
  while ((k + 1) * (k + 2) <= t) ++k;
  while (k * (k + 1) > t) --k;
  int s, c;
  if (t < (k + 1) * (k + 1)) { s = 2 * k;     c = t - k * (k + 1); }
  else                       { s = 2 * k + 1; c = t - (k + 1) * (k + 1); }
  const int b = blockIdx.z;
  gemm64_sc(Qb + b * SD, xb + b * SD, P + b * SSQ, l + b * SS,
            SS, DD, s * 64, c * 128, 16, As, Bs);
}

// ---------------------------------------------------------------- PV GEMM (128^2, balanced pairs, R13-exact)
// Grid (64,1,4): c = x&7 (128-wide D col-tile), pr = x>>3 (strip pair).
// Block does strip 15-pr (nk=2(16-pr)) then strip pr (nk=2(pr+1)):
// exactly 34 K-tiles per block, 256 blocks.
__global__ __launch_bounds__(256, 2) void gemm_pv128(const bf16* __restrict__ P,
                                                     const bf16* __restrict__ Vt,
                                                     float* __restrict__ l,
                                                     float* __restrict__ out) {
  extern __shared__ bf16 lds[];
  bf16* As = lds;            // [3][128][64] = 48KB
  bf16* Bs = lds + 24576;    // [2][128][64] = 32KB
  const long long SD = (long long)SS * DD;
  const long long SSQ = (long long)SS * SS;
  const int c  = blockIdx.x & 7;
  const int pr = blockIdx.x >> 3;
  const int b  = blockIdx.z;
  const int n0 = c * 128;
  const int rL = 15 - pr;
  gemm128_pv(P + b * SSQ, Vt + b * SD, out + b * SD, l + b * SS,
             DD, SS, rL * 128, n0, 2 * (rL + 1), As, Bs);
  __syncthreads();
  gemm128_pv(P + b * SSQ, Vt + b * SD, out + b * SD, l + b * SS,
             DD, SS, pr * 128, n0, 2 * (pr + 1), As, Bs);
}

// ---------------------------------------------------------------- launch
extern "C" void kernel_launch(void* const* d_in, const int* in_sizes, int n_in,
                              void* d_out, int out_size, void* d_ws, size_t ws_size,
                              hipStream_t stream) {
  const float* x  = (const float*)d_in[0];  // [4,2048,1024]
  const float* qk = (const float*)d_in[1];  // [1024,1024]
  const float* ov = (const float*)d_in[2];  // [1024,1024]
  float* out = (float*)d_out;               // [4,2048,1024] fp32

  char* ws = (char*)d_ws;
  const size_t MB = 1ull << 20;
  bf16*  xb  = (bf16*)(ws + 0);          // 16 MB
  bf16*  qkT = (bf16*)(ws + 16 * MB);    //  2 MB
  bf16*  ovT = (bf16*)(ws + 18 * MB);    //  2 MB
  bf16*  Qb  = (bf16*)(ws + 20 * MB);    // 16 MB
  bf16*  Vt  = (bf16*)(ws + 36 * MB);    // 16 MB  V^T per batch [D, S]
  bf16*  P   = (bf16*)(ws + 52 * MB);    // 32 MB  P' = exp(s/32) bf16
  float* l   = (float*)(ws + 84 * MB);   // 32 KB  row sums [B][S]

  static bool lds_opt_in = false;
  if (!lds_opt_in) {
    hipFuncSetAttribute((const void*)gemm_qv256,
                        hipFuncAttributeMaxDynamicSharedMemorySize, 131072);
    hipFuncSetAttribute((const void*)gemm_sc64,
                        hipFuncAttributeMaxDynamicSharedMemorySize, 49152);
    hipFuncSetAttribute((const void*)gemm_pv128,
                        hipFuncAttributeMaxDynamicSharedMemorySize, 81920);
    lds_opt_in = true;
  }

  prep_kernel<<<dim3(8712), 256, 0, stream>>>(x, xb, qk, qkT, ov, ovT, l);
  gemm_qv256<<<dim3(32, 1, 8), 512, 131072, stream>>>(xb, qkT, ovT, Qb, Vt);
  gemm_sc64<<<dim3(272, 1, 4), 256, 49152, stream>>>(Qb, xb, P, l);
  gemm_pv128<<<dim3(64, 1, 4), 256, 81920, stream>>>(P, Vt, l, out);
}